// Round 1
// baseline (286.069 us; speedup 1.0000x reference)
//
#include <hip/hip_runtime.h>

// LSTM B=8192, T=512, I=1, H=32; out[b] = h_T . W_lin + b_lin.  All I/O f32.
//
// R15: 2-wave-per-group / 2-groups-per-block (convoy killer).
// Theory: R13's 801 cyc/step wall = serial chain + ~300 cyc of 4-wave barrier
// convoy (each wave's pre-barrier tail randomly delayed by the co-resident
// wave of the OTHER block on its SIMD; evidence: convoy scales with waves:
// 8-wave=190us > 4-wave=171us; busy 547 < wall 801 with no contention).
// Fix: wave owns 16 hiddens (4 custom tiles, 4 MFMAs, 4 hiddens/lane);
// 2 waves per group, 2 groups per 256-thread block; grid 256 = 1 block/CU
// -> 1 wave/SIMD: no cross-wave issue interference, minimal barrier skew.
// x staged in 128-step double-buffered LDS chunks (2 groups of full-T f32
// don't fit 64KB static LDS). Activation math byte-identical to R13
// (paired rcp, pkrtz pack). NOTE: packed f32x2 (v_pk_*) acts failed the
// post-timing determinism check in R12 - do not reintroduce.
//
// Ledger (dur_us): dot2-VALU 490 -> mfma 1-wave 360 -> 2-wave 297 -> 4-wave
// trans-split 215 -> 8-wave custom 190 -> 4-wave custom 171/179 -> this.
// Predict ~130-145; if ~175+ the wall is pure dataflow -> attack trans chain.

#define L2E 1.4426950408889634f

typedef _Float16 f16x8 __attribute__((ext_vector_type(8)));
typedef float    f32x4 __attribute__((ext_vector_type(4)));

__global__ __launch_bounds__(256, 1) void lstm_2w2g(
    const float* __restrict__ x,      // [B*512]
    const float* __restrict__ W_ih,   // [128]
    const float* __restrict__ W_hh,   // [128*32]
    const float* __restrict__ b_ih,   // [128]
    const float* __restrict__ b_hh,   // [128]
    const float* __restrict__ W_lin,  // [32]
    const float* __restrict__ b_lin,  // [1]
    float* __restrict__ out)          // [B]
{
    __shared__ float xs[2][2][128][16];                      // [group][chunkbuf][t][b], stride 16: reads conflict-free
    __shared__ __align__(16) unsigned int hb[2][2][16 * 20]; // [group][stepbuf], h half2, col-stride 20 dwords
    __shared__ float ps[64];                                 // epilogue partials

    const int tid  = threadIdx.x;
    const int wv   = tid >> 6;          // 0..3
    const int ga   = wv >> 1;           // group 0/1 (waves 0,1 | 2,3)
    const int wvg  = wv & 1;            // wave within group: owns hiddens [16wvg,16wvg+16)
    const int lane = tid & 63;
    const int col  = lane & 15;         // batch within group
    const int quad = lane >> 4;         // 0..3
    const int ltid = tid & 127;         // thread within group
    const int base = blockIdx.x * 32 + ga * 16;

    // ---- stage x chunk 0 (t 0..127) for this group ----
    {
        const float* gx = x + (size_t)base * 512;
        #pragma unroll
        for (int i = 0; i < 4; ++i) {
            int idx = i * 128 + ltid;          // 0..511 float4s of the chunk
            int b   = idx >> 5;                // batch 0..15
            int tq  = idx & 31;                // float4 index in 128-t window
            float4 v = ((const float4*)(gx + (size_t)b * 512))[tq];
            int t0 = tq * 4;
            xs[ga][0][t0 + 0][b] = v.x;
            xs[ga][0][t0 + 1][b] = v.y;
            xs[ga][0][t0 + 2][b] = v.z;
            xs[ga][0][t0 + 3][b] = v.w;
        }
    }

    // ---- custom A-tiles: MFMA m (0..3): A-row rho holds W_hh gate-row
    // G(rho)=32*(rho&3)+16wvg+4*(rho>>2)+m, so lane(quad,col) acc[m] slot r
    // = gate r of hidden j=16wvg+4quad+m (row-permuting A permutes D rows). ----
    f16x8 wA[4];
    {
        const int rt = col & 3;                               // gate type of A-row col
        const int a  = col >> 2;
        const float s = (rt == 2) ? (2.0f * L2E) : L2E;
        #pragma unroll
        for (int m = 0; m < 4; ++m) {
            const int grow = 32 * rt + 16 * wvg + 4 * a + m;
            #pragma unroll
            for (int j = 0; j < 8; ++j)
                wA[m][j] = (_Float16)(W_hh[grow * 32 + quad * 8 + j] * s);
        }
    }

    float wih[4][4], bia[4][4];
    #pragma unroll
    for (int m = 0; m < 4; ++m)
        #pragma unroll
        for (int r = 0; r < 4; ++r) {
            const float s = (r == 2) ? (2.0f * L2E) : L2E;
            const int g = 32 * r + 16 * wvg + 4 * quad + m;
            wih[m][r] = W_ih[g] * s;
            bia[m][r] = (b_ih[g] + b_hh[g]) * s;
        }

    __syncthreads();

    float c0 = 0.f, c1 = 0.f, c2 = 0.f, c3 = 0.f;
    float hl0 = 0.f, hl1 = 0.f, hl2 = 0.f, hl3 = 0.f;
    f16x8 bfrag = {};                   // h = 0
    f32x4 cq[4];
    {
        float xt = xs[ga][0][0][col];   // t = 0
        #pragma unroll
        for (int m = 0; m < 4; ++m)
            #pragma unroll
            for (int r = 0; r < 4; ++r)
                cq[m][r] = fmaf(xt, wih[m][r], bia[m][r]);
    }

    // h-pair write base: pairs (j0,j0+1),(j0+2,j0+3), j0=16wvg+4quad -> dwords 8wvg+2quad, +1
    const int wr = col * 20 + 8 * wvg + 2 * quad;

    for (int t = 0; t < 512; ++t) {
        // ---- stage next 128-t x chunk (at t=0,128,256; ~0.3us each, 3x) ----
        if ((t & 127) == 0 && t < 384) {
            const int ck = (t >> 7) + 1;
            const int cb = ck & 1;
            const float* gx = x + (size_t)base * 512 + ck * 128;
            #pragma unroll
            for (int i = 0; i < 4; ++i) {
                int idx = i * 128 + ltid;
                int b   = idx >> 5;
                int tq  = idx & 31;
                float4 v = ((const float4*)(gx + (size_t)b * 512))[tq];
                int t0 = tq * 4;
                xs[ga][cb][t0 + 0][b] = v.x;
                xs[ga][cb][t0 + 1][b] = v.y;
                xs[ga][cb][t0 + 2][b] = v.z;
                xs[ga][cb][t0 + 3][b] = v.w;
            }
        }

        unsigned int* buf = hb[ga][t & 1];

        f32x4 a0 = __builtin_amdgcn_mfma_f32_16x16x32_f16(wA[0], bfrag, cq[0], 0, 0, 0);
        f32x4 a1 = __builtin_amdgcn_mfma_f32_16x16x32_f16(wA[1], bfrag, cq[1], 0, 0, 0);
        f32x4 a2 = __builtin_amdgcn_mfma_f32_16x16x32_f16(wA[2], bfrag, cq[2], 0, 0, 0);
        f32x4 a3 = __builtin_amdgcn_mfma_f32_16x16x32_f16(wA[3], bfrag, cq[3], 0, 0, 0);

        const int rt1 = t + 1;
        float xt1 = xs[ga][(rt1 >> 7) & 1][rt1 & 127][col];   // prefetch next x

        // ---- fused activations, pair (j0, j0+1); rcps PAIRED (as R13) ----
        float ei0 = __builtin_amdgcn_exp2f(-a0[0]);
        float ef0 = __builtin_amdgcn_exp2f(-a0[1]);
        float eg0 = __builtin_amdgcn_exp2f(-a0[2]);
        float eo0 = __builtin_amdgcn_exp2f(-a0[3]);
        float ei1 = __builtin_amdgcn_exp2f(-a1[0]);
        float ef1 = __builtin_amdgcn_exp2f(-a1[1]);
        float eg1 = __builtin_amdgcn_exp2f(-a1[2]);
        float eo1 = __builtin_amdgcn_exp2f(-a1[3]);
        float aI0 = 1.0f + ei0, aF0 = 1.0f + ef0, aG0 = 1.0f + eg0, aO0 = 1.0f + eo0;
        float aI1 = 1.0f + ei1, aF1 = 1.0f + ef1, aG1 = 1.0f + eg1, aO1 = 1.0f + eo1;
        float tIG0 = aI0 * aG0, tIG1 = aI1 * aG1;
        float num0 = fmaf(c0, tIG0, (1.0f - eg0) * aF0);
        float num1 = fmaf(c1, tIG1, (1.0f - eg1) * aF1);
        float D0 = aF0 * tIG0, D1 = aF1 * tIG1;
        float rD = __builtin_amdgcn_rcpf(D0 * D1);
        c0 = num0 * (rD * D1);
        c1 = num1 * (rD * D0);
        float ec0 = __builtin_amdgcn_exp2f(c0 * (-2.0f * L2E));
        float ec1 = __builtin_amdgcn_exp2f(c1 * (-2.0f * L2E));
        float H0 = aO0 * (1.0f + ec0), H1 = aO1 * (1.0f + ec1);
        float rH = __builtin_amdgcn_rcpf(H0 * H1);
        hl0 = (1.0f - ec0) * (rH * H1);
        hl1 = (1.0f - ec1) * (rH * H0);
        unsigned int pkA = __builtin_bit_cast(unsigned int, __builtin_amdgcn_cvt_pkrtz(hl0, hl1));

        // ---- pair (j0+2, j0+3) ----
        float ei2 = __builtin_amdgcn_exp2f(-a2[0]);
        float ef2 = __builtin_amdgcn_exp2f(-a2[1]);
        float eg2 = __builtin_amdgcn_exp2f(-a2[2]);
        float eo2 = __builtin_amdgcn_exp2f(-a2[3]);
        float ei3 = __builtin_amdgcn_exp2f(-a3[0]);
        float ef3 = __builtin_amdgcn_exp2f(-a3[1]);
        float eg3 = __builtin_amdgcn_exp2f(-a3[2]);
        float eo3 = __builtin_amdgcn_exp2f(-a3[3]);
        float aI2 = 1.0f + ei2, aF2 = 1.0f + ef2, aG2 = 1.0f + eg2, aO2 = 1.0f + eo2;
        float aI3 = 1.0f + ei3, aF3 = 1.0f + ef3, aG3 = 1.0f + eg3, aO3 = 1.0f + eo3;
        float tIG2 = aI2 * aG2, tIG3 = aI3 * aG3;
        float num2 = fmaf(c2, tIG2, (1.0f - eg2) * aF2);
        float num3 = fmaf(c3, tIG3, (1.0f - eg3) * aF3);
        float D2 = aF2 * tIG2, D3 = aF3 * tIG3;
        float rD2 = __builtin_amdgcn_rcpf(D2 * D3);
        c2 = num2 * (rD2 * D3);
        c3 = num3 * (rD2 * D2);
        float ec2 = __builtin_amdgcn_exp2f(c2 * (-2.0f * L2E));
        float ec3 = __builtin_amdgcn_exp2f(c3 * (-2.0f * L2E));
        float H2 = aO2 * (1.0f + ec2), H3 = aO3 * (1.0f + ec3);
        float rH2 = __builtin_amdgcn_rcpf(H2 * H3);
        hl2 = (1.0f - ec2) * (rH2 * H3);
        hl3 = (1.0f - ec3) * (rH2 * H2);
        unsigned int pkB = __builtin_bit_cast(unsigned int, __builtin_amdgcn_cvt_pkrtz(hl2, hl3));

        // adjacent hidden pairs -> one b64 write
        uint2 w2; w2.x = pkA; w2.y = pkB;
        *(uint2*)&buf[wr] = w2;

        // next step's C-init in the pre-barrier slack
        #pragma unroll
        for (int m = 0; m < 4; ++m)
            #pragma unroll
            for (int r = 0; r < 4; ++r)
                cq[m][r] = fmaf(xt1, wih[m][r], bia[m][r]);

        __syncthreads();
        // B-frag: pairs quad*4..+3 of batch col = k quad*8..quad*8+7
        uint4 bv = *(const uint4*)&buf[col * 20 + quad * 4];
        bfrag = __builtin_bit_cast(f16x8, bv);
    }

    // ---- epilogue: out[b] = sum_j h_j * W_lin[j] + b_lin ----
    const int j0 = 16 * wvg + 4 * quad;
    float v = hl0 * W_lin[j0 + 0];
    v = fmaf(hl1, W_lin[j0 + 1], v);
    v = fmaf(hl2, W_lin[j0 + 2], v);
    v = fmaf(hl3, W_lin[j0 + 3], v);
    v += __shfl_xor(v, 16);            // combine quads
    v += __shfl_xor(v, 32);
    if (lane < 16) ps[wv * 16 + col] = v;   // = ps[ga*32 + wvg*16 + col]
    __syncthreads();
    if (tid < 32) {
        const int g2 = tid >> 4, cc = tid & 15;
        out[blockIdx.x * 32 + tid] = b_lin[0] + ps[g2 * 32 + cc] + ps[g2 * 32 + 16 + cc];
    }
}

extern "C" void kernel_launch(void* const* d_in, const int* in_sizes, int n_in,
                              void* d_out, int out_size, void* d_ws, size_t ws_size,
                              hipStream_t stream) {
    const float* x     = (const float*)d_in[0];
    const float* W_ih  = (const float*)d_in[1];
    const float* W_hh  = (const float*)d_in[2];
    const float* b_ih  = (const float*)d_in[3];
    const float* b_hh  = (const float*)d_in[4];
    const float* W_lin = (const float*)d_in[5];
    const float* b_lin = (const float*)d_in[6];
    float* out = (float*)d_out;

    const int B = in_sizes[0] / 512;   // 8192
    dim3 grid(B / 32), block(256);
    lstm_2w2g<<<grid, block, 0, stream>>>(x, W_ih, W_hh, b_ih, b_hh, W_lin, b_lin, out);
}